// Round 2
// baseline (657.582 us; speedup 1.0000x reference)
//
#include <hip/hip_runtime.h>
#include <hip/hip_bf16.h>

// Binary BasicBlock. conv(sign,sign) via bf16 MFMA (exact). This round:
// conv-patch LDS staging (stage A halo patch ONCE per cb, all 9 taps read
// from it -> 288 MFMA per barrier pair), global_load_lds width-16 staging
// with XOR-granule swizzle (bank-conflict-free ds_read_b128), B fragments
// direct global->VGPR from a pre-packed per-lane-contiguous layout.

#define CCH  256
#define PIMG 3136      // 56*56
#define MTOT 100352    // 32*3136
#define SPIX 3364      // 58*58
#define WPAD 58

typedef __attribute__((ext_vector_type(8))) short short8;
typedef __attribute__((ext_vector_type(4))) float floatx4;

#define GLOAD16(gp, lp) __builtin_amdgcn_global_load_lds( \
    (const __attribute__((address_space(1))) unsigned int*)(gp), \
    (__attribute__((address_space(3))) unsigned int*)(lp), 16, 0, 0)

// ---------------- kernel 1: transpose + binarize x -> spad[cb][n][pix][64] --
__global__ void transpose_sign(const float* __restrict__ x,
                               const float* __restrict__ b11,
                               unsigned short* __restrict__ spad) {
    const int hp = blockIdx.x;          // 0..57
    const int cb = blockIdx.y;          // 0..3
    const int n  = blockIdx.z;          // 0..31
    const int t  = threadIdx.x;         // 256
    __shared__ float tile[64 * 57];

    const bool border_h = (hp == 0) || (hp == 57);
    if (!border_h) {
        const int h = hp - 1;
        for (int it = 0; it < 14; ++it) {           // 64 ch * 56 cols
            int lin = t + it * 256;
            int row = lin / 56;
            int col = lin - row * 56;
            int cg  = cb * 64 + row;
            float v = x[((size_t)(n * CCH + cg)) * PIMG + h * 56 + col] + b11[cg];
            tile[row * 57 + col] = (v > 0.f) ? 1.f : ((v < 0.f) ? -1.f : 0.f);
        }
    }
    __syncthreads();
    for (int it = 0; it < 15; ++it) {               // 58 wp * 64 c
        int lin = t + it * 256;
        if (lin >= 58 * 64) break;
        int wp = lin >> 6;
        int c  = lin & 63;
        float s = 0.f;
        if (!border_h && wp >= 1 && wp <= 56) s = tile[c * 57 + (wp - 1)];
        unsigned short us = (s > 0.f) ? 0x3F80 : ((s < 0.f) ? 0xBF80 : 0);
        spad[(((size_t)cb * 32 + n) * SPIX + hp * WPAD + wp) * 64 + c] = us;
    }
}

// ---------------- kernel 2: weight binarize (fragment-packed) + BN fold -----
// wqB block = (r9*4+cb)*8 + nb*4+wn*2+ks, 2048 el: [l16][quad][j][8]
// wq1B block = cb*8 + nb*4+wn*2+ks, same inner layout
__global__ void prep_w(const float* __restrict__ w3, const float* __restrict__ w1,
                       const float* __restrict__ g1, const float* __restrict__ be1,
                       const float* __restrict__ m1, const float* __restrict__ v1,
                       const float* __restrict__ g2, const float* __restrict__ be2,
                       const float* __restrict__ m2, const float* __restrict__ v2,
                       unsigned short* __restrict__ wqB, unsigned short* __restrict__ wq1B,
                       float* __restrict__ k2s, float* __restrict__ k2b,
                       float* __restrict__ k3s, float* __restrict__ k3b) {
    const int o = blockIdx.x;   // 0..511
    const int t = threadIdx.x;  // 256
    __shared__ float red[256];
    if (o < 256) {
        const int nb = o >> 7, wn = (o >> 6) & 1, j = (o >> 4) & 3, l16 = o & 15;
        const float* wp = w3 + (size_t)o * 2304;
        float s = 0.f;
        for (int i = t; i < 2304; i += 256) s += fabsf(wp[i]);
        red[t] = s; __syncthreads();
        for (int k = 128; k > 0; k >>= 1) { if (t < k) red[t] += red[t + k]; __syncthreads(); }
        float scale = red[0] * (1.0f / 2304.0f);
        for (int i = t; i < 2304; i += 256) {
            int c = i / 9; int r9 = i - c * 9;
            int cb = c >> 6, ks = (c >> 5) & 1, quad = (c >> 3) & 3, e = c & 7;
            float w = wp[i];
            size_t idx = (size_t)((r9 * 4 + cb) * 8 + nb * 4 + wn * 2 + ks) * 2048
                       + l16 * 128 + quad * 32 + j * 8 + e;
            wqB[idx] = (w > 0.f) ? 0x3F80 : ((w < 0.f) ? 0xBF80 : 0);
        }
        if (t == 0) {
            float inv = g1[o] * rsqrtf(v1[o] + 1e-5f);
            k2s[o] = scale * inv;
            k2b[o] = be1[o] - m1[o] * inv;
        }
    } else {
        const int o1 = o - 256;
        const int nb = o1 >> 7, wn = (o1 >> 6) & 1, j = (o1 >> 4) & 3, l16 = o1 & 15;
        const int c = t;
        const int cb = c >> 6, ks = (c >> 5) & 1, quad = (c >> 3) & 3, e = c & 7;
        float w = w1[(size_t)o1 * 256 + c];
        red[t] = fabsf(w); __syncthreads();
        for (int k = 128; k > 0; k >>= 1) { if (t < k) red[t] += red[t + k]; __syncthreads(); }
        float scale = red[0] * (1.0f / 256.0f);
        size_t idx = (size_t)(cb * 8 + nb * 4 + wn * 2 + ks) * 2048
                   + l16 * 128 + quad * 32 + j * 8 + e;
        wq1B[idx] = (w > 0.f) ? 0x3F80 : ((w < 0.f) ? 0xBF80 : 0);
        if (t == 0) {
            float inv = g2[o1] * rsqrtf(v2[o1] + 1e-5f);
            k3s[o1] = scale * inv;
            k3b[o1] = be2[o1] - m2[o1] * inv;
        }
    }
}

// ---------------- kernel 3: 3x3 binary conv, conv-patch implicit GEMM -------
// grid (25 tiles, 32 n, 2 nb). A patch: 256 padded-pixel rows x 64 ch in LDS.
__global__ __launch_bounds__(256, 3) void gemm3x3(
    const unsigned short* __restrict__ spad, const unsigned short* __restrict__ wqB,
    const float* __restrict__ x,
    const float* __restrict__ k2s, const float* __restrict__ k2b,
    const float* __restrict__ b12, const float* __restrict__ b13,
    const float* __restrict__ b21, const float* __restrict__ a1,
    float* __restrict__ out1, unsigned short* __restrict__ sgn) {
    __shared__ __align__(16) unsigned short As[256 * 64];   // 32 KB
    const int t    = threadIdx.x;
    const int tile = blockIdx.x;    // 0..24
    const int n    = blockIdx.y;    // 0..31
    const int nb   = blockIdx.z;    // 0..1
    const int lane = t & 63;
    const int wid  = t >> 6;
    const int wm   = wid & 1;
    const int wn   = wid >> 1;
    const int quad = lane >> 4;
    const int l16  = lane & 15;

    const int p0t    = tile * 128;
    const int h0     = p0t / 56;
    const int w0     = p0t - h0 * 56;
    const int pstart = h0 * WPAD + w0;

    // fragment padded-row offsets (relative to pstart), per i
    int prow[4];
    for (int i = 0; i < 4; ++i) {
        int p = p0t + wm * 64 + i * 16 + l16;
        int h = p / 56, w = p - h * 56;
        prow[i] = h * WPAD + w - pstart;
    }

    // staging geometry: per round k, wave stages 8 rows (1 KB) lane-contiguous
    const int rbase = wid * 8 + (lane >> 3);       // row mod 32
    const int gsw   = (lane & 7) ^ (rbase & 7);    // XOR swizzle in global addr

    floatx4 acc[4][4] = {};

    for (int cb = 0; cb < 4; ++cb) {
        const size_t cbase = ((size_t)(cb * 32 + n)) * SPIX + pstart;
        #pragma unroll
        for (int k = 0; k < 8; ++k) {
            const int row = k * 32 + rbase;        // row&7 == rbase&7
            const unsigned short* gp = spad + (cbase + row) * 64 + gsw * 8;
            GLOAD16(gp, &As[(k * 4 + wid) * 512]);
        }
        __syncthreads();
        #pragma unroll
        for (int r9 = 0; r9 < 9; ++r9) {
            const int shift = (r9 / 3) * WPAD + (r9 % 3);
            #pragma unroll
            for (int ks = 0; ks < 2; ++ks) {
                const short8* bp8 = (const short8*)(wqB +
                    (size_t)((r9 * 4 + cb) * 8 + nb * 4 + wn * 2 + ks) * 2048 +
                    l16 * 128 + quad * 32);
                short8 bf[4];
                #pragma unroll
                for (int j = 0; j < 4; ++j) bf[j] = bp8[j];
                short8 af[4];
                #pragma unroll
                for (int i = 0; i < 4; ++i) {
                    const int r  = prow[i] + shift;
                    const int gg = (ks * 4 + quad) ^ (r & 7);
                    af[i] = *(const short8*)(&As[r * 64 + gg * 8]);
                }
                #pragma unroll
                for (int i = 0; i < 4; ++i)
                    #pragma unroll
                    for (int j = 0; j < 4; ++j)
                        acc[i][j] = __builtin_amdgcn_mfma_f32_16x16x32_bf16(
                            af[i], bf[j], acc[i][j], 0, 0, 0);
            }
        }
        __syncthreads();
    }

    // epilogue: out1 = prelu(x + bn, a1)+b13 -> d_out; sign(out1+b21) -> sgn
    for (int j = 0; j < 4; ++j) {
        const int o = nb * 128 + wn * 64 + j * 16 + l16;
        const float sc = k2s[o], bt = k2b[o];
        const float v12 = b12[o], v13 = b13[o], v21 = b21[o], va = a1[o];
        const size_t sgnb = (size_t)(o >> 6) * ((size_t)MTOT * 64) + (o & 63);
        for (int i = 0; i < 4; ++i) {
            const int p0 = p0t + wm * 64 + i * 16 + quad * 4;
            if (p0 >= PIMG) continue;              // padded-tile guard
            const size_t goff = ((size_t)(n * CCH + o)) * PIMG + p0;
            const float4 xv = *(const float4*)(x + goff);
            float rr[4] = {xv.x, xv.y, xv.z, xv.w};
            float res[4];
            for (int r = 0; r < 4; ++r) {
                float v  = acc[i][j][r] * sc + bt + rr[r];
                float tt = v + v12;
                float o1 = ((tt > 0.f) ? tt : va * tt) + v13;
                res[r] = o1;
                float s = o1 + v21;
                sgn[sgnb + (size_t)(n * PIMG + p0 + r) * 64] =
                    (s > 0.f) ? 0x3F80 : ((s < 0.f) ? 0xBF80 : 0);
            }
            float4 ov; ov.x = res[0]; ov.y = res[1]; ov.z = res[2]; ov.w = res[3];
            *(float4*)(out1 + goff) = ov;
        }
    }
}

// ---------------- kernel 4: 1x1 binary conv GEMM + final epilogue -----------
__global__ __launch_bounds__(256, 3) void gemm1x1(
    const unsigned short* __restrict__ sgnA, const unsigned short* __restrict__ wq1B,
    const float* __restrict__ k3s, const float* __restrict__ k3b,
    const float* __restrict__ b22, const float* __restrict__ b23,
    const float* __restrict__ a2,
    float* __restrict__ out) {
    __shared__ __align__(16) unsigned short As[128 * 64];   // 16 KB
    const int t    = threadIdx.x;
    const int mb   = blockIdx.x;    // 0..783
    const int nb   = blockIdx.y;    // 0..1
    const int lane = t & 63;
    const int wid  = t >> 6;
    const int wm   = wid & 1;
    const int wn   = wid >> 1;
    const int quad = lane >> 4;
    const int l16  = lane & 15;

    const int rbase = wid * 8 + (lane >> 3);
    const int gsw   = (lane & 7) ^ (rbase & 7);

    floatx4 acc[4][4] = {};
    int rloc[4];
    for (int i = 0; i < 4; ++i) rloc[i] = wm * 64 + i * 16 + l16;

    for (int cb = 0; cb < 4; ++cb) {
        #pragma unroll
        for (int k = 0; k < 4; ++k) {
            const int row = k * 32 + rbase;
            const unsigned short* gp = sgnA +
                ((size_t)cb * MTOT + (size_t)mb * 128 + row) * 64 + gsw * 8;
            GLOAD16(gp, &As[(k * 4 + wid) * 512]);
        }
        __syncthreads();
        #pragma unroll
        for (int ks = 0; ks < 2; ++ks) {
            const short8* bp8 = (const short8*)(wq1B +
                (size_t)(cb * 8 + nb * 4 + wn * 2 + ks) * 2048 +
                l16 * 128 + quad * 32);
            short8 bf[4];
            #pragma unroll
            for (int j = 0; j < 4; ++j) bf[j] = bp8[j];
            short8 af[4];
            #pragma unroll
            for (int i = 0; i < 4; ++i) {
                const int r  = rloc[i];
                const int gg = (ks * 4 + quad) ^ (r & 7);
                af[i] = *(const short8*)(&As[r * 64 + gg * 8]);
            }
            #pragma unroll
            for (int i = 0; i < 4; ++i)
                #pragma unroll
                for (int j = 0; j < 4; ++j)
                    acc[i][j] = __builtin_amdgcn_mfma_f32_16x16x32_bf16(
                        af[i], bf[j], acc[i][j], 0, 0, 0);
        }
        __syncthreads();
    }

    for (int j = 0; j < 4; ++j) {
        const int o = nb * 128 + wn * 64 + j * 16 + l16;
        const float sc = k3s[o], bt = k3b[o];
        const float v22 = b22[o], v23 = b23[o], va = a2[o];
        for (int i = 0; i < 4; ++i) {
            const int m0 = mb * 128 + wm * 64 + i * 16 + quad * 4;
            const int n_img = m0 / PIMG;
            const int p0 = m0 - n_img * PIMG;
            const size_t goff = (size_t)(n_img * CCH + o) * PIMG + p0;
            const float4 o1v = *(const float4*)(out + goff);
            float rr[4] = {o1v.x, o1v.y, o1v.z, o1v.w};
            float res[4];
            for (int r = 0; r < 4; ++r) {
                float v  = acc[i][j][r] * sc + bt + rr[r];
                float tt = v + v22;
                res[r] = ((tt > 0.f) ? tt : va * tt) + v23;
            }
            float4 ov; ov.x = res[0]; ov.y = res[1]; ov.z = res[2]; ov.w = res[3];
            *(float4*)(out + goff) = ov;
        }
    }
}

// ---------------- launch ---------------------------------------------------
extern "C" void kernel_launch(void* const* d_in, const int* in_sizes, int n_in,
                              void* d_out, int out_size, void* d_ws, size_t ws_size,
                              hipStream_t stream) {
    const float* x   = (const float*)d_in[0];
    const float* w3  = (const float*)d_in[1];
    const float* w1  = (const float*)d_in[2];
    const float* b11 = (const float*)d_in[3];
    const float* b12 = (const float*)d_in[4];
    const float* b13 = (const float*)d_in[5];
    const float* b21 = (const float*)d_in[6];
    const float* b22 = (const float*)d_in[7];
    const float* b23 = (const float*)d_in[8];
    const float* g1  = (const float*)d_in[9];
    const float* be1 = (const float*)d_in[10];
    const float* m1  = (const float*)d_in[11];
    const float* v1  = (const float*)d_in[12];
    const float* g2  = (const float*)d_in[13];
    const float* be2 = (const float*)d_in[14];
    const float* m2  = (const float*)d_in[15];
    const float* v2  = (const float*)d_in[16];
    const float* a1  = (const float*)d_in[17];
    const float* a2  = (const float*)d_in[18];
    float* out = (float*)d_out;

    char* ws = (char*)d_ws;
    // spad:  4*32*3364*64*2 = 55,107,584 B  (+64 KB staging-overrun slack)
    // sgn:   4*100352*64*2  = 51,380,224 B
    // wqB:   589824*2       =  1,179,648 B
    // wq1B:  65536*2        =    131,072 B
    unsigned short* spad = (unsigned short*)(ws);
    unsigned short* sgn  = (unsigned short*)(ws + 55173120);
    unsigned short* wqB  = (unsigned short*)(ws + 106553344);
    unsigned short* wq1B = (unsigned short*)(ws + 107732992);
    float* k2s = (float*)(ws + 107864064);
    float* k2b = k2s + 256;
    float* k3s = k2s + 512;
    float* k3b = k2s + 768;

    transpose_sign<<<dim3(58, 4, 32), 256, 0, stream>>>(x, b11, spad);
    prep_w<<<512, 256, 0, stream>>>(w3, w1, g1, be1, m1, v1, g2, be2, m2, v2,
                                    wqB, wq1B, k2s, k2b, k3s, k3b);
    gemm3x3<<<dim3(25, 32, 2), 256, 0, stream>>>(spad, wqB, x, k2s, k2b,
                                                 b12, b13, b21, a1, out, sgn);
    gemm1x1<<<dim3(784, 2), 256, 0, stream>>>(sgn, wq1B, k3s, k3b,
                                              b22, b23, a2, out);
}

// Round 3
// 499.086 us; speedup vs baseline: 1.3176x; 1.3176x over previous
//
#include <hip/hip_runtime.h>
#include <hip/hip_bf16.h>

// Binary BasicBlock. conv(sign,sign) via bf16 MFMA (exact).
// R3: round-1 barrier cadence (B in LDS, 32 MFMA/wave per phase) +
//     A halo patch resident per cb (no 9x A restage) +
//     global_load_lds width-16 staging for A and B +
//     XOR-granule swizzle (conflict-free ds_read_b128).

#define CCH  256
#define PIMG 3136      // 56*56
#define MTOT 100352    // 32*3136
#define SPIX 3364      // 58*58
#define WPAD 58

typedef __attribute__((ext_vector_type(8))) short short8;
typedef __attribute__((ext_vector_type(4))) float floatx4;

#define GLOAD16(gp, lp) __builtin_amdgcn_global_load_lds( \
    (const __attribute__((address_space(1))) unsigned int*)(gp), \
    (__attribute__((address_space(3))) unsigned int*)(lp), 16, 0, 0)

// ---------------- kernel 1: transpose + binarize x -> spad[cb][n][pix][64] --
__global__ void transpose_sign(const float* __restrict__ x,
                               const float* __restrict__ b11,
                               unsigned short* __restrict__ spad) {
    const int hp = blockIdx.x;          // 0..57
    const int cb = blockIdx.y;          // 0..3
    const int n  = blockIdx.z;          // 0..31
    const int t  = threadIdx.x;         // 256
    __shared__ float tile[64 * 57];

    const bool border_h = (hp == 0) || (hp == 57);
    if (!border_h) {
        const int h = hp - 1;
        for (int it = 0; it < 14; ++it) {           // 64 ch * 56 cols
            int lin = t + it * 256;
            int row = lin / 56;
            int col = lin - row * 56;
            int cg  = cb * 64 + row;
            float v = x[((size_t)(n * CCH + cg)) * PIMG + h * 56 + col] + b11[cg];
            tile[row * 57 + col] = (v > 0.f) ? 1.f : ((v < 0.f) ? -1.f : 0.f);
        }
    }
    __syncthreads();
    for (int it = 0; it < 15; ++it) {               // 58 wp * 64 c
        int lin = t + it * 256;
        if (lin >= 58 * 64) break;
        int wp = lin >> 6;
        int c  = lin & 63;
        float s = 0.f;
        if (!border_h && wp >= 1 && wp <= 56) s = tile[c * 57 + (wp - 1)];
        unsigned short us = (s > 0.f) ? 0x3F80 : ((s < 0.f) ? 0xBF80 : 0);
        spad[(((size_t)cb * 32 + n) * SPIX + hp * WPAD + wp) * 64 + c] = us;
    }
}

// ---------------- kernel 2: weight binarize + BN fold -----------------------
// wq3t[(r9*4+cb)*256 + o][64c], wq1t[cb*256 + o][64c]
__global__ void prep_w(const float* __restrict__ w3, const float* __restrict__ w1,
                       const float* __restrict__ g1, const float* __restrict__ be1,
                       const float* __restrict__ m1, const float* __restrict__ v1,
                       const float* __restrict__ g2, const float* __restrict__ be2,
                       const float* __restrict__ m2, const float* __restrict__ v2,
                       unsigned short* __restrict__ wq3t, unsigned short* __restrict__ wq1t,
                       float* __restrict__ k2s, float* __restrict__ k2b,
                       float* __restrict__ k3s, float* __restrict__ k3b) {
    const int o = blockIdx.x;   // 0..511
    const int t = threadIdx.x;  // 256
    __shared__ float red[256];
    if (o < 256) {
        const float* wp = w3 + (size_t)o * 2304;
        float s = 0.f;
        for (int i = t; i < 2304; i += 256) s += fabsf(wp[i]);
        red[t] = s; __syncthreads();
        for (int k = 128; k > 0; k >>= 1) { if (t < k) red[t] += red[t + k]; __syncthreads(); }
        float scale = red[0] * (1.0f / 2304.0f);
        for (int i = t; i < 2304; i += 256) {
            int c = i / 9; int r9 = i - c * 9;
            float w = wp[i];
            wq3t[((size_t)((r9 * 4 + (c >> 6)) * 256 + o)) * 64 + (c & 63)] =
                (w > 0.f) ? 0x3F80 : ((w < 0.f) ? 0xBF80 : 0);
        }
        if (t == 0) {
            float inv = g1[o] * rsqrtf(v1[o] + 1e-5f);
            k2s[o] = scale * inv;
            k2b[o] = be1[o] - m1[o] * inv;
        }
    } else {
        const int o1 = o - 256;
        float w = w1[(size_t)o1 * 256 + t];
        red[t] = fabsf(w); __syncthreads();
        for (int k = 128; k > 0; k >>= 1) { if (t < k) red[t] += red[t + k]; __syncthreads(); }
        float scale = red[0] * (1.0f / 256.0f);
        wq1t[((size_t)((t >> 6) * 256 + o1)) * 64 + (t & 63)] =
            (w > 0.f) ? 0x3F80 : ((w < 0.f) ? 0xBF80 : 0);
        if (t == 0) {
            float inv = g2[o1] * rsqrtf(v2[o1] + 1e-5f);
            k3s[o1] = scale * inv;
            k3b[o1] = be2[o1] - m2[o1] * inv;
        }
    }
}

// ---------------- kernel 3: 3x3 binary conv, patch-resident implicit GEMM ---
// grid (25 tiles, 32 n, 2 nb). A patch 256 rows x 64 ch (32 KB) per cb;
// B tile 128 o x 64 c (16 KB) per (r9,cb) phase. 48 KB LDS, 3 blocks/CU.
__global__ __launch_bounds__(256, 3) void gemm3x3(
    const unsigned short* __restrict__ spad, const unsigned short* __restrict__ wq3t,
    const float* __restrict__ x,
    const float* __restrict__ k2s, const float* __restrict__ k2b,
    const float* __restrict__ b12, const float* __restrict__ b13,
    const float* __restrict__ b21, const float* __restrict__ a1,
    float* __restrict__ out1, unsigned short* __restrict__ sgn) {
    __shared__ __align__(16) unsigned short As[256 * 64];   // 32 KB
    __shared__ __align__(16) unsigned short Bs[128 * 64];   // 16 KB
    const int t    = threadIdx.x;
    const int tile = blockIdx.x;    // 0..24
    const int n    = blockIdx.y;    // 0..31
    const int nb   = blockIdx.z;    // 0..1
    const int lane = t & 63;
    const int wid  = t >> 6;
    const int wm   = wid & 1;
    const int wn   = wid >> 1;
    const int quad = lane >> 4;
    const int l16  = lane & 15;

    const int p0t    = tile * 128;
    const int h0     = p0t / 56;
    const int w0     = p0t - h0 * 56;
    const int pstart = h0 * WPAD + w0;

    int prow[4];
    for (int i = 0; i < 4; ++i) {
        int p = p0t + wm * 64 + i * 16 + l16;
        int h = p / 56, w = p - h * 56;
        prow[i] = h * WPAD + w - pstart;
    }

    const int rbase = wid * 8 + (lane >> 3);       // row mod 32
    const int gsw   = (lane & 7) ^ (rbase & 7);    // XOR swizzle in global addr

    floatx4 acc[4][4] = {};

    for (int cb = 0; cb < 4; ++cb) {
        // stage A patch (once per cb): 256 rows
        const size_t cbase = ((size_t)(cb * 32 + n)) * SPIX + pstart;
        #pragma unroll
        for (int k = 0; k < 8; ++k) {
            const int row = k * 32 + rbase;
            const unsigned short* gp = spad + (cbase + row) * 64 + gsw * 8;
            GLOAD16(gp, &As[(k * 4 + wid) * 512]);
        }
        #pragma unroll
        for (int r9 = 0; r9 < 9; ++r9) {
            // stage B tile (per r9,cb): 128 rows
            #pragma unroll
            for (int k = 0; k < 4; ++k) {
                const int row = k * 32 + rbase;
                const unsigned short* gp = wq3t +
                    ((size_t)((r9 * 4 + cb) * 256 + nb * 128 + row)) * 64 + gsw * 8;
                GLOAD16(gp, &Bs[(k * 4 + wid) * 512]);
            }
            __syncthreads();
            const int shift = (r9 / 3) * WPAD + (r9 % 3);
            #pragma unroll
            for (int ks = 0; ks < 2; ++ks) {
                short8 af[4], bf[4];
                #pragma unroll
                for (int i = 0; i < 4; ++i) {
                    const int r  = prow[i] + shift;
                    const int gg = (ks * 4 + quad) ^ (r & 7);
                    af[i] = *(const short8*)(&As[r * 64 + gg * 8]);
                }
                #pragma unroll
                for (int j = 0; j < 4; ++j) {
                    const int ro = wn * 64 + j * 16 + l16;
                    const int gg = (ks * 4 + quad) ^ (ro & 7);
                    bf[j] = *(const short8*)(&Bs[ro * 64 + gg * 8]);
                }
                #pragma unroll
                for (int i = 0; i < 4; ++i)
                    #pragma unroll
                    for (int j = 0; j < 4; ++j)
                        acc[i][j] = __builtin_amdgcn_mfma_f32_16x16x32_bf16(
                            af[i], bf[j], acc[i][j], 0, 0, 0);
            }
            __syncthreads();
        }
    }

    // epilogue: out1 = prelu(x + bn, a1)+b13 -> d_out; sign(out1+b21) -> sgn
    for (int j = 0; j < 4; ++j) {
        const int o = nb * 128 + wn * 64 + j * 16 + l16;
        const float sc = k2s[o], bt = k2b[o];
        const float v12 = b12[o], v13 = b13[o], v21 = b21[o], va = a1[o];
        const size_t sgnb = (size_t)(o >> 6) * ((size_t)MTOT * 64) + (o & 63);
        for (int i = 0; i < 4; ++i) {
            const int p0 = p0t + wm * 64 + i * 16 + quad * 4;
            if (p0 >= PIMG) continue;              // padded-tile guard
            const size_t goff = ((size_t)(n * CCH + o)) * PIMG + p0;
            const float4 xv = *(const float4*)(x + goff);
            float rr[4] = {xv.x, xv.y, xv.z, xv.w};
            float res[4];
            for (int r = 0; r < 4; ++r) {
                float v  = acc[i][j][r] * sc + bt + rr[r];
                float tt = v + v12;
                float o1 = ((tt > 0.f) ? tt : va * tt) + v13;
                res[r] = o1;
                float s = o1 + v21;
                sgn[sgnb + (size_t)(n * PIMG + p0 + r) * 64] =
                    (s > 0.f) ? 0x3F80 : ((s < 0.f) ? 0xBF80 : 0);
            }
            float4 ov; ov.x = res[0]; ov.y = res[1]; ov.z = res[2]; ov.w = res[3];
            *(float4*)(out1 + goff) = ov;
        }
    }
}

// ---------------- kernel 4: 1x1 binary conv GEMM + final epilogue -----------
__global__ __launch_bounds__(256, 3) void gemm1x1(
    const unsigned short* __restrict__ sgnA, const unsigned short* __restrict__ wq1t,
    const float* __restrict__ k3s, const float* __restrict__ k3b,
    const float* __restrict__ b22, const float* __restrict__ b23,
    const float* __restrict__ a2,
    float* __restrict__ out) {
    __shared__ __align__(16) unsigned short As[128 * 64];   // 16 KB
    __shared__ __align__(16) unsigned short Bs[128 * 64];   // 16 KB
    const int t    = threadIdx.x;
    const int mb   = blockIdx.x;    // 0..783
    const int nb   = blockIdx.y;    // 0..1
    const int lane = t & 63;
    const int wid  = t >> 6;
    const int wm   = wid & 1;
    const int wn   = wid >> 1;
    const int quad = lane >> 4;
    const int l16  = lane & 15;

    const int rbase = wid * 8 + (lane >> 3);
    const int gsw   = (lane & 7) ^ (rbase & 7);

    floatx4 acc[4][4] = {};

    for (int cb = 0; cb < 4; ++cb) {
        #pragma unroll
        for (int k = 0; k < 4; ++k) {
            const int row = k * 32 + rbase;
            const unsigned short* gp = sgnA +
                ((size_t)cb * MTOT + (size_t)mb * 128 + row) * 64 + gsw * 8;
            GLOAD16(gp, &As[(k * 4 + wid) * 512]);
        }
        #pragma unroll
        for (int k = 0; k < 4; ++k) {
            const int row = k * 32 + rbase;
            const unsigned short* gp = wq1t +
                ((size_t)(cb * 256 + nb * 128 + row)) * 64 + gsw * 8;
            GLOAD16(gp, &Bs[(k * 4 + wid) * 512]);
        }
        __syncthreads();
        #pragma unroll
        for (int ks = 0; ks < 2; ++ks) {
            short8 af[4], bf[4];
            #pragma unroll
            for (int i = 0; i < 4; ++i) {
                const int r  = wm * 64 + i * 16 + l16;
                const int gg = (ks * 4 + quad) ^ (l16 & 7);
                af[i] = *(const short8*)(&As[r * 64 + gg * 8]);
            }
            #pragma unroll
            for (int j = 0; j < 4; ++j) {
                const int ro = wn * 64 + j * 16 + l16;
                const int gg = (ks * 4 + quad) ^ (l16 & 7);
                bf[j] = *(const short8*)(&Bs[ro * 64 + gg * 8]);
            }
            #pragma unroll
            for (int i = 0; i < 4; ++i)
                #pragma unroll
                for (int j = 0; j < 4; ++j)
                    acc[i][j] = __builtin_amdgcn_mfma_f32_16x16x32_bf16(
                        af[i], bf[j], acc[i][j], 0, 0, 0);
        }
        __syncthreads();
    }

    for (int j = 0; j < 4; ++j) {
        const int o = nb * 128 + wn * 64 + j * 16 + l16;
        const float sc = k3s[o], bt = k3b[o];
        const float v22 = b22[o], v23 = b23[o], va = a2[o];
        for (int i = 0; i < 4; ++i) {
            const int m0 = mb * 128 + wm * 64 + i * 16 + quad * 4;
            const int n_img = m0 / PIMG;
            const int p0 = m0 - n_img * PIMG;
            const size_t goff = (size_t)(n_img * CCH + o) * PIMG + p0;
            const float4 o1v = *(const float4*)(out + goff);
            float rr[4] = {o1v.x, o1v.y, o1v.z, o1v.w};
            float res[4];
            for (int r = 0; r < 4; ++r) {
                float v  = acc[i][j][r] * sc + bt + rr[r];
                float tt = v + v22;
                res[r] = ((tt > 0.f) ? tt : va * tt) + v23;
            }
            float4 ov; ov.x = res[0]; ov.y = res[1]; ov.z = res[2]; ov.w = res[3];
            *(float4*)(out + goff) = ov;
        }
    }
}

// ---------------- launch ---------------------------------------------------
extern "C" void kernel_launch(void* const* d_in, const int* in_sizes, int n_in,
                              void* d_out, int out_size, void* d_ws, size_t ws_size,
                              hipStream_t stream) {
    const float* x   = (const float*)d_in[0];
    const float* w3  = (const float*)d_in[1];
    const float* w1  = (const float*)d_in[2];
    const float* b11 = (const float*)d_in[3];
    const float* b12 = (const float*)d_in[4];
    const float* b13 = (const float*)d_in[5];
    const float* b21 = (const float*)d_in[6];
    const float* b22 = (const float*)d_in[7];
    const float* b23 = (const float*)d_in[8];
    const float* g1  = (const float*)d_in[9];
    const float* be1 = (const float*)d_in[10];
    const float* m1  = (const float*)d_in[11];
    const float* v1  = (const float*)d_in[12];
    const float* g2  = (const float*)d_in[13];
    const float* be2 = (const float*)d_in[14];
    const float* m2  = (const float*)d_in[15];
    const float* v2  = (const float*)d_in[16];
    const float* a1  = (const float*)d_in[17];
    const float* a2  = (const float*)d_in[18];
    float* out = (float*)d_out;

    char* ws = (char*)d_ws;
    // spad:  4*32*3364*64*2 = 55,107,584 B (+64 KB staging-overrun slack)
    // sgn:   4*100352*64*2  = 51,380,224 B
    // wq3t:  9*4*256*64*2   =  1,179,648 B
    // wq1t:  4*256*64*2     =    131,072 B
    unsigned short* spad = (unsigned short*)(ws);
    unsigned short* sgn  = (unsigned short*)(ws + 55173120);
    unsigned short* wq3t = (unsigned short*)(ws + 106553344);
    unsigned short* wq1t = (unsigned short*)(ws + 107732992);
    float* k2s = (float*)(ws + 107864064);
    float* k2b = k2s + 256;
    float* k3s = k2s + 512;
    float* k3b = k2s + 768;

    transpose_sign<<<dim3(58, 4, 32), 256, 0, stream>>>(x, b11, spad);
    prep_w<<<512, 256, 0, stream>>>(w3, w1, g1, be1, m1, v1, g2, be2, m2, v2,
                                    wq3t, wq1t, k2s, k2b, k3s, k3b);
    gemm3x3<<<dim3(25, 32, 2), 256, 0, stream>>>(spad, wq3t, x, k2s, k2b,
                                                 b12, b13, b21, a1, out, sgn);
    gemm1x1<<<dim3(784, 2), 256, 0, stream>>>(sgn, wq1t, k3s, k3b,
                                              b22, b23, a2, out);
}

// Round 4
// 449.594 us; speedup vs baseline: 1.4626x; 1.1101x over previous
//
#include <hip/hip_runtime.h>
#include <hip/hip_bf16.h>

// Binary BasicBlock. conv(sign,sign) via i8 MFMA (exact i32 accumulate).
// R4: mfma_i32_16x16x64_i8 (2x K, half bytes), full N=256 per block,
// K-group=128: 18 phases x 64 MFMA/wave per barrier pair in gemm3x3.

#define CCH  256
#define PIMG 3136      // 56*56
#define MTOT 100352    // 32*3136
#define SPIX 3364      // 58*58
#define WPAD 58

typedef __attribute__((ext_vector_type(4))) int intx4;

#define GLOAD16(gp, lp) __builtin_amdgcn_global_load_lds( \
    (const __attribute__((address_space(1))) unsigned int*)(gp), \
    (__attribute__((address_space(3))) unsigned int*)(lp), 16, 0, 0)

__device__ __forceinline__ signed char sgnc(float v) {
    return (v > 0.f) ? 1 : ((v < 0.f) ? -1 : 0);
}

// ---------------- kernel 1: transpose + binarize x -> spad[cbg][n][pix][128]
__global__ void transpose_sign(const float* __restrict__ x,
                               const float* __restrict__ b11,
                               signed char* __restrict__ spad) {
    const int hp  = blockIdx.x;         // 0..57
    const int cbg = blockIdx.y;         // 0..1 (128 ch each)
    const int n   = blockIdx.z;         // 0..31
    const int t   = threadIdx.x;        // 256
    __shared__ __align__(16) signed char tile[128 * 60];

    const bool border_h = (hp == 0) || (hp == 57);
    if (!border_h) {
        const int h = hp - 1;
        for (int it = 0; it < 7; ++it) {            // 128 ch * 14 col4
            int lin  = t + it * 256;
            int c    = lin / 14;
            int col4 = lin - c * 14;
            int cg   = cbg * 128 + c;
            const float4 xv = *(const float4*)(x +
                ((size_t)(n * CCH + cg)) * PIMG + h * 56 + col4 * 4);
            float bb = b11[cg];
            int w = (sgnc(xv.x + bb) & 0xff)
                  | ((sgnc(xv.y + bb) & 0xff) << 8)
                  | ((sgnc(xv.z + bb) & 0xff) << 16)
                  | ((sgnc(xv.w + bb) & 0xff) << 24);
            *(int*)(&tile[c * 60 + col4 * 4]) = w;
        }
    }
    __syncthreads();
    for (int it = 0; it < 8; ++it) {                // 58 wp * 32 c4
        int lin = t + it * 256;
        if (lin >= 58 * 32) break;
        int wp = lin >> 5;
        int c  = (lin & 31) * 4;
        int w  = 0;
        if (!border_h && wp >= 1 && wp <= 56) {
            signed char s0 = tile[(c + 0) * 60 + (wp - 1)];
            signed char s1 = tile[(c + 1) * 60 + (wp - 1)];
            signed char s2 = tile[(c + 2) * 60 + (wp - 1)];
            signed char s3 = tile[(c + 3) * 60 + (wp - 1)];
            w = (s0 & 0xff) | ((s1 & 0xff) << 8) | ((s2 & 0xff) << 16) | ((s3 & 0xff) << 24);
        }
        *(int*)(spad + (((size_t)cbg * 32 + n) * SPIX + hp * WPAD + wp) * 128 + c) = w;
    }
}

// ---------------- kernel 2: weight binarize + BN fold -----------------------
// wq3t[(r9*2+cbg)*256 + o][128c] i8, wq1t[cbg*256 + o][128c] i8
__global__ void prep_w(const float* __restrict__ w3, const float* __restrict__ w1,
                       const float* __restrict__ g1, const float* __restrict__ be1,
                       const float* __restrict__ m1, const float* __restrict__ v1,
                       const float* __restrict__ g2, const float* __restrict__ be2,
                       const float* __restrict__ m2, const float* __restrict__ v2,
                       signed char* __restrict__ wq3t, signed char* __restrict__ wq1t,
                       float* __restrict__ k2s, float* __restrict__ k2b,
                       float* __restrict__ k3s, float* __restrict__ k3b) {
    const int o = blockIdx.x;   // 0..511
    const int t = threadIdx.x;  // 256
    __shared__ float red[256];
    if (o < 256) {
        const float* wp = w3 + (size_t)o * 2304;
        float s = 0.f;
        for (int i = t; i < 2304; i += 256) s += fabsf(wp[i]);
        red[t] = s; __syncthreads();
        for (int k = 128; k > 0; k >>= 1) { if (t < k) red[t] += red[t + k]; __syncthreads(); }
        float scale = red[0] * (1.0f / 2304.0f);
        for (int i = t; i < 2304; i += 256) {
            int c = i / 9; int r9 = i - c * 9;
            wq3t[((size_t)((r9 * 2 + (c >> 7)) * 256 + o)) * 128 + (c & 127)] = sgnc(wp[i]);
        }
        if (t == 0) {
            float inv = g1[o] * rsqrtf(v1[o] + 1e-5f);
            k2s[o] = scale * inv;
            k2b[o] = be1[o] - m1[o] * inv;
        }
    } else {
        const int o1 = o - 256;
        float w = w1[(size_t)o1 * 256 + t];
        red[t] = fabsf(w); __syncthreads();
        for (int k = 128; k > 0; k >>= 1) { if (t < k) red[t] += red[t + k]; __syncthreads(); }
        float scale = red[0] * (1.0f / 256.0f);
        wq1t[((size_t)((t >> 7) * 256 + o1)) * 128 + (t & 127)] = sgnc(w);
        if (t == 0) {
            float inv = g2[o1] * rsqrtf(v2[o1] + 1e-5f);
            k3s[o1] = scale * inv;
            k3b[o1] = be2[o1] - m2[o1] * inv;
        }
    }
}

// ---------------- kernel 3: 3x3 binary conv, i8 patch-resident GEMM ---------
// grid (25 tiles, 32 n). Full N=256. A patch 256 rows x 128 c (32 KB) per cbg;
// B tile 256 o x 128 c (32 KB) per (r9,cbg). 64 KB LDS, 2 blocks/CU.
__global__ __launch_bounds__(256, 2) void gemm3x3(
    const signed char* __restrict__ spad, const signed char* __restrict__ wq3t,
    const float* __restrict__ x,
    const float* __restrict__ k2s, const float* __restrict__ k2b,
    const float* __restrict__ b12, const float* __restrict__ b13,
    const float* __restrict__ b21, const float* __restrict__ a1,
    float* __restrict__ out1, signed char* __restrict__ sgn) {
    __shared__ __align__(16) signed char As[256 * 128];   // 32 KB
    __shared__ __align__(16) signed char Bs[256 * 128];   // 32 KB
    const int t    = threadIdx.x;
    const int tile = blockIdx.x;    // 0..24
    const int n    = blockIdx.y;    // 0..31
    const int lane = t & 63;
    const int wid  = t >> 6;
    const int wm   = wid & 1;
    const int wn   = wid >> 1;
    const int quad = lane >> 4;
    const int l16  = lane & 15;

    const int p0t    = tile * 128;
    const int h0     = p0t / 56;
    const int w0     = p0t - h0 * 56;
    const int pstart = h0 * WPAD + w0;

    int prow[4];
    for (int i = 0; i < 4; ++i) {
        int p = p0t + wm * 64 + i * 16 + l16;
        int h = p / 56, w = p - h * 56;
        prow[i] = h * WPAD + w - pstart;
    }

    const int rbase = wid * 8 + (lane >> 3);       // row mod 32
    const int gsw   = (lane & 7) ^ (rbase & 7);    // XOR swizzle in global addr

    intx4 acc[4][8] = {};

    for (int cbg = 0; cbg < 2; ++cbg) {
        // stage A patch (once per cbg): 256 rows x 128 B
        const size_t cbase = ((size_t)(cbg * 32 + n)) * SPIX + pstart;
        #pragma unroll
        for (int k = 0; k < 8; ++k) {
            const int row = k * 32 + rbase;
            const signed char* gp = spad + (cbase + row) * 128 + gsw * 16;
            GLOAD16(gp, &As[(k * 4 + wid) * 1024]);
        }
        #pragma unroll
        for (int r9 = 0; r9 < 9; ++r9) {
            // stage B tile: 256 rows x 128 B
            #pragma unroll
            for (int k = 0; k < 8; ++k) {
                const int row = k * 32 + rbase;
                const signed char* gp = wq3t +
                    ((size_t)((r9 * 2 + cbg) * 256 + row)) * 128 + gsw * 16;
                GLOAD16(gp, &Bs[(k * 4 + wid) * 1024]);
            }
            __syncthreads();
            const int shift = (r9 / 3) * WPAD + (r9 % 3);
            #pragma unroll
            for (int ks = 0; ks < 2; ++ks) {
                intx4 af[4], bf[8];
                #pragma unroll
                for (int i = 0; i < 4; ++i) {
                    const int r  = prow[i] + shift;
                    const int gg = (ks * 4 + quad) ^ (r & 7);
                    af[i] = *(const intx4*)(&As[r * 128 + gg * 16]);
                }
                #pragma unroll
                for (int j = 0; j < 8; ++j) {
                    const int ro = wn * 128 + j * 16 + l16;
                    const int gg = (ks * 4 + quad) ^ (ro & 7);
                    bf[j] = *(const intx4*)(&Bs[ro * 128 + gg * 16]);
                }
                #pragma unroll
                for (int i = 0; i < 4; ++i)
                    #pragma unroll
                    for (int j = 0; j < 8; ++j)
                        acc[i][j] = __builtin_amdgcn_mfma_i32_16x16x64_i8(
                            af[i], bf[j], acc[i][j], 0, 0, 0);
            }
            __syncthreads();
        }
    }

    // epilogue: out1 = prelu(x + bn, a1)+b13 -> d_out; sign(out1+b21) -> sgn i8
    for (int j = 0; j < 8; ++j) {
        const int o = wn * 128 + j * 16 + l16;
        const float sc = k2s[o], bt = k2b[o];
        const float v12 = b12[o], v13 = b13[o], v21 = b21[o], va = a1[o];
        for (int i = 0; i < 4; ++i) {
            const int p0 = p0t + wm * 64 + i * 16 + quad * 4;
            if (p0 >= PIMG) continue;              // padded-tile guard
            const size_t goff = ((size_t)(n * CCH + o)) * PIMG + p0;
            const float4 xv = *(const float4*)(x + goff);
            float rr[4] = {xv.x, xv.y, xv.z, xv.w};
            float res[4];
            for (int r = 0; r < 4; ++r) {
                float v  = (float)acc[i][j][r] * sc + bt + rr[r];
                float tt = v + v12;
                float o1 = ((tt > 0.f) ? tt : va * tt) + v13;
                res[r] = o1;
                sgn[((size_t)(n * PIMG + p0 + r)) * 256 + o] = sgnc(o1 + v21);
            }
            float4 ov; ov.x = res[0]; ov.y = res[1]; ov.z = res[2]; ov.w = res[3];
            *(float4*)(out1 + goff) = ov;
        }
    }
}

// ---------------- kernel 4: 1x1 binary conv GEMM + final epilogue -----------
__global__ __launch_bounds__(256, 2) void gemm1x1(
    const signed char* __restrict__ sgnA, const signed char* __restrict__ wq1t,
    const float* __restrict__ k3s, const float* __restrict__ k3b,
    const float* __restrict__ b22, const float* __restrict__ b23,
    const float* __restrict__ a2,
    float* __restrict__ out) {
    __shared__ __align__(16) signed char As[128 * 128];   // 16 KB
    __shared__ __align__(16) signed char Bs[256 * 128];   // 32 KB
    const int t    = threadIdx.x;
    const int mb   = blockIdx.x;    // 0..783
    const int lane = t & 63;
    const int wid  = t >> 6;
    const int wm   = wid & 1;
    const int wn   = wid >> 1;
    const int quad = lane >> 4;
    const int l16  = lane & 15;

    const int rbase = wid * 8 + (lane >> 3);
    const int gsw   = (lane & 7) ^ (rbase & 7);

    intx4 acc[4][8] = {};

    for (int cbg = 0; cbg < 2; ++cbg) {
        #pragma unroll
        for (int k = 0; k < 4; ++k) {
            const int row = k * 32 + rbase;
            const signed char* gp = sgnA +
                ((size_t)(mb * 128 + row)) * 256 + cbg * 128 + gsw * 16;
            GLOAD16(gp, &As[(k * 4 + wid) * 1024]);
        }
        #pragma unroll
        for (int k = 0; k < 8; ++k) {
            const int row = k * 32 + rbase;
            const signed char* gp = wq1t +
                ((size_t)(cbg * 256 + row)) * 128 + gsw * 16;
            GLOAD16(gp, &Bs[(k * 4 + wid) * 1024]);
        }
        __syncthreads();
        #pragma unroll
        for (int ks = 0; ks < 2; ++ks) {
            intx4 af[4], bf[8];
            #pragma unroll
            for (int i = 0; i < 4; ++i) {
                const int r  = wm * 64 + i * 16 + l16;
                const int gg = (ks * 4 + quad) ^ (r & 7);
                af[i] = *(const intx4*)(&As[r * 128 + gg * 16]);
            }
            #pragma unroll
            for (int j = 0; j < 8; ++j) {
                const int ro = wn * 128 + j * 16 + l16;
                const int gg = (ks * 4 + quad) ^ (ro & 7);
                bf[j] = *(const intx4*)(&Bs[ro * 128 + gg * 16]);
            }
            #pragma unroll
            for (int i = 0; i < 4; ++i)
                #pragma unroll
                for (int j = 0; j < 8; ++j)
                    acc[i][j] = __builtin_amdgcn_mfma_i32_16x16x64_i8(
                        af[i], bf[j], acc[i][j], 0, 0, 0);
        }
        __syncthreads();
    }

    for (int j = 0; j < 8; ++j) {
        const int o = wn * 128 + j * 16 + l16;
        const float sc = k3s[o], bt = k3b[o];
        const float v22 = b22[o], v23 = b23[o], va = a2[o];
        for (int i = 0; i < 4; ++i) {
            const int m0 = mb * 128 + wm * 64 + i * 16 + quad * 4;
            const int n_img = m0 / PIMG;
            const int p0 = m0 - n_img * PIMG;
            const size_t goff = (size_t)(n_img * CCH + o) * PIMG + p0;
            const float4 o1v = *(const float4*)(out + goff);
            float rr[4] = {o1v.x, o1v.y, o1v.z, o1v.w};
            float res[4];
            for (int r = 0; r < 4; ++r) {
                float v  = (float)acc[i][j][r] * sc + bt + rr[r];
                float tt = v + v22;
                res[r] = ((tt > 0.f) ? tt : va * tt) + v23;
            }
            float4 ov; ov.x = res[0]; ov.y = res[1]; ov.z = res[2]; ov.w = res[3];
            *(float4*)(out + goff) = ov;
        }
    }
}

// ---------------- launch ---------------------------------------------------
extern "C" void kernel_launch(void* const* d_in, const int* in_sizes, int n_in,
                              void* d_out, int out_size, void* d_ws, size_t ws_size,
                              hipStream_t stream) {
    const float* x   = (const float*)d_in[0];
    const float* w3  = (const float*)d_in[1];
    const float* w1  = (const float*)d_in[2];
    const float* b11 = (const float*)d_in[3];
    const float* b12 = (const float*)d_in[4];
    const float* b13 = (const float*)d_in[5];
    const float* b21 = (const float*)d_in[6];
    const float* b22 = (const float*)d_in[7];
    const float* b23 = (const float*)d_in[8];
    const float* g1  = (const float*)d_in[9];
    const float* be1 = (const float*)d_in[10];
    const float* m1  = (const float*)d_in[11];
    const float* v1  = (const float*)d_in[12];
    const float* g2  = (const float*)d_in[13];
    const float* be2 = (const float*)d_in[14];
    const float* m2  = (const float*)d_in[15];
    const float* v2  = (const float*)d_in[16];
    const float* a1  = (const float*)d_in[17];
    const float* a2  = (const float*)d_in[18];
    float* out = (float*)d_out;

    char* ws = (char*)d_ws;
    // spad:  2*32*3364*128 i8 = 27,553,792 B (+256 KB staging-overrun slack)
    // sgn:   100352*256 i8    = 25,690,112 B
    // wq3t:  18*256*128 i8    =    589,824 B
    // wq1t:  2*256*128 i8     =     65,536 B
    signed char* spad = (signed char*)(ws);
    signed char* sgn  = (signed char*)(ws + 27816192);
    signed char* wq3t = (signed char*)(ws + 53506304);
    signed char* wq1t = (signed char*)(ws + 54096128);
    float* k2s = (float*)(ws + 54161664);
    float* k2b = k2s + 256;
    float* k3s = k2s + 512;
    float* k3b = k2s + 768;

    transpose_sign<<<dim3(58, 2, 32), 256, 0, stream>>>(x, b11, spad);
    prep_w<<<512, 256, 0, stream>>>(w3, w1, g1, be1, m1, v1, g2, be2, m2, v2,
                                    wq3t, wq1t, k2s, k2b, k3s, k3b);
    gemm3x3<<<dim3(25, 32), 256, 0, stream>>>(spad, wq3t, x, k2s, k2b,
                                              b12, b13, b21, a1, out, sgn);
    gemm1x1<<<dim3(784), 256, 0, stream>>>(sgn, wq1t, k3s, k3b,
                                           b22, b23, a2, out);
}